// Round 1
// baseline (306.734 us; speedup 1.0000x reference)
//
#include <hip/hip_runtime.h>
#include <cmath>
#include <complex>
#include <algorithm>

// ---------------- compile-time path metadata ----------------
#define NPATH 15
// Paths in reference order: for l1 in {0,1,2}, l2 in {0,1,2}, l3 valid.
constexpr int PL1[NPATH] = {0,0,0, 1,1,1,1,1,1, 2,2,2,2,2,2};
constexpr int PL2[NPATH] = {0,1,2, 0,1,1,1,2,2, 0,1,1,2,2,2};
constexpr int PL3[NPATH] = {0,1,2, 1,0,1,2,1,2, 2,1,2,0,1,2};
// cg flat offsets (sizes d1*d2*d3): 1,9,25,9,9,27,45,45,75,25,45,75,25,75,125
constexpr int CGOFF[NPATH] = {0,1,10,35,44,53,80,125,170,245,270,315,390,415,490};
constexpr int CGTOT = 615;
// yC offsets per n (sizes d1*d3): 1,3,5,9,3,9,15,9,15,25,15,25,5,15,25
constexpr int YCOFF[NPATH] = {0,1,4,9,18,21,30,45,54,69,94,109,134,139,154};
constexpr int YCTOT = 179;
constexpr int XOFF[3] = {0,64,256};   // x segment base per l1
constexpr int YOFF[3] = {0,1,4};      // y segment base per l2
constexpr int KKB[3]  = {0,1,4};      // acc kk base per l3

struct CGArg { float v[CGTOT]; };     // alpha-scaled real-basis CG, by-value kernarg

// ---------------- host: exact port of reference CG construction ----------------
static double factd(int n){ double r=1.0; for(int i=2;i<=n;++i) r*=(double)i; return r; }

static double su2_cg(int j1,int m1,int j2,int m2,int j3,int m3){
  if (m3 != m1+m2) return 0.0;
  double c = (double)(2*j3+1) * factd(j1+j2-j3) * factd(j1-j2+j3) * factd(-j1+j2+j3)
             / factd(j1+j2+j3+1);
  c = std::sqrt(c);
  c *= std::sqrt(factd(j3+m3)*factd(j3-m3)*factd(j1-m1)*factd(j1+m1)*factd(j2-m2)*factd(j2+m2));
  double s = 0.0;
  int kmin = std::max(0, std::max(j2-j3-m1, j1-j3+m2));
  int kmax = std::min(j1+j2-j3, std::min(j1-m1, j2+m2));
  for (int k=kmin;k<=kmax;++k){
    double d = factd(k)*factd(j1+j2-j3-k)*factd(j1-m1-k)*factd(j2+m2-k)
             * factd(j3-j2+m1+k)*factd(j3-j1-m2+k);
    s += ((k&1)? -1.0 : 1.0)/d;
  }
  return c*s;
}

static void qmat(int l, std::complex<double>* q){ // row-major (2l+1)x(2l+1); rows=complex m, cols=real idx
  int d = 2*l+1;
  for (int a=0;a<d*d;++a) q[a] = std::complex<double>(0.0,0.0);
  const double r2 = 1.0/std::sqrt(2.0);
  for (int m=-l; m<0; ++m){
    q[(l+m)*d + (l-m)] = std::complex<double>(r2, 0.0);   // col l+|m|
    q[(l+m)*d + (l+m)] = std::complex<double>(0.0, -r2);  // col l-|m|
  }
  q[l*d + l] = std::complex<double>(1.0,0.0);
  for (int m=1; m<=l; ++m){
    double sg = (m&1)? -1.0 : 1.0;
    q[(l+m)*d + (l+m)] = std::complex<double>(sg*r2, 0.0);
    q[(l+m)*d + (l-m)] = std::complex<double>(0.0, sg*r2);
  }
  std::complex<double> ph = (l==0)? std::complex<double>(1,0)
                        : (l==1)? std::complex<double>(0,-1)
                                : std::complex<double>(-1,0);   // (-i)^l
  for (int a=0;a<d*d;++a) q[a] *= ph;
}

static void compute_cg(float* outv){
  const int npaths_to[3] = {3,6,6};
  for (int p=0;p<NPATH;++p){
    int l1=PL1[p], l2=PL2[p], l3=PL3[p];
    int d1=2*l1+1, d2=2*l2+1, d3=2*l3+1;
    std::complex<double> C[5][5][5];
    for (int a=0;a<5;++a) for(int b=0;b<5;++b) for(int c=0;c<5;++c) C[a][b][c]=std::complex<double>(0,0);
    for (int m1=-l1;m1<=l1;++m1) for (int m2=-l2;m2<=l2;++m2){
      int m3=m1+m2;
      if (std::abs(m3)<=l3) C[l1+m1][l2+m2][l3+m3] = su2_cg(l1,m1,l2,m2,l3,m3);
    }
    std::complex<double> U1[25],U2[25],U3[25];
    qmat(l1,U1); qmat(l2,U2); qmat(l3,U3);
    double Cr[5][5][5]; double nrm=0.0;
    for (int a=0;a<d1;++a) for (int b=0;b<d2;++b) for (int c=0;c<d3;++c){
      std::complex<double> s(0,0);
      for (int i=0;i<d1;++i) for (int j=0;j<d2;++j) for (int k=0;k<d3;++k)
        s += U1[i*d1+a]*U2[j*d2+b]*std::conj(U3[k*d3+c])*C[i][j][k];
      Cr[a][b][c] = s.real();
      nrm += s.real()*s.real();
    }
    nrm = std::sqrt(nrm);
    double alpha = 1.0/std::sqrt(64.0*(double)npaths_to[l3]);  // path normalization folded in
    float* o = outv + CGOFF[p];
    int idx=0;
    for (int a=0;a<d1;++a) for (int b=0;b<d2;++b) for (int c=0;c<d3;++c)
      o[idx++] = (float)(Cr[a][b][c]/nrm*alpha);
  }
}

// ---------------- device kernel ----------------
constexpr int BN = 16;   // batch rows per block

__global__ __launch_bounds__(256, 2)
void tp_kernel(const float* __restrict__ x, const float* __restrict__ y,
               const float* __restrict__ W, float* __restrict__ out, CGArg cga)
{
  __shared__ float s_cg[CGTOT];
  __shared__ float s_y[BN][9];
  __shared__ float s_yc[BN][YCTOT];
  __shared__ float s_z[BN*65*8];   // per-path Z, nl-padded (65) to break bank aliasing

  const int tid = threadIdx.x;
  const int n0 = blockIdx.x * BN;

  for (int i=tid;i<CGTOT;i+=256) s_cg[i] = cga.v[i];
  for (int i=tid;i<BN*9;i+=256){
    int nl=i/9, j=i-nl*9;
    s_y[nl][j] = y[(size_t)(n0+nl)*9 + j];
  }
  __syncthreads();

  // ---- stage 1: yC[nl][i,k] = sum_j y[j]*CG[i,j,k], all paths, once ----
  #pragma unroll
  for (int p=0;p<NPATH;++p){
    const int l2=PL2[p], l3=PL3[p], l1=PL1[p];
    const int d1=2*l1+1, d2=2*l2+1, d3=2*l3+1;
    const int cnt = BN*d1*d3;
    for (int idx=tid; idx<cnt; idx+=256){
      int nl = idx/(d1*d3);
      int r  = idx - nl*(d1*d3);
      int i  = r/d3;
      int k  = r - i*d3;
      float s = 0.f;
      #pragma unroll
      for (int j=0;j<d2;++j)
        s += s_y[nl][YOFF[l2]+j] * s_cg[CGOFF[p] + (i*d2+j)*d3 + k];
      s_yc[nl][YCOFF[p] + i*d3 + k] = s;
    }
  }

  float acc[4][9];
  #pragma unroll
  for (int a=0;a<4;++a){
    #pragma unroll
    for (int b=0;b<9;++b) acc[a][b]=0.f;
  }

  const int w4  = tid & 15;   // w block: w = w4*4 .. w4*4+3
  const int nl3 = tid >> 4;   // this thread's batch row in stage 3

  #pragma unroll
  for (int p=0;p<NPATH;++p){
    const int l1=PL1[p], l3=PL3[p];
    const int d1=2*l1+1, d3=2*l3+1;
    const int ZS = (l3==2)?8:((l3==1)?4:1);
    __syncthreads();   // prev stage-3 done with s_z (and at p=0: yC ready)

    // ---- stage 2: Z[nl][u][k] = sum_i x[nl][u,i]*yC[nl][i,k] ----
    #pragma unroll
    for (int it=0; it<(BN*64)/256; ++it){
      int idx = it*256 + tid;
      int u  = idx & 63;
      int nl = idx >> 6;            // wave-uniform -> yC reads broadcast
      const float* xp = x + (size_t)(n0+nl)*576 + XOFF[l1] + u*d1;
      float z[5];
      #pragma unroll
      for (int k=0;k<d3;++k) z[k]=0.f;
      #pragma unroll
      for (int i=0;i<d1;++i){
        float xv = xp[i];
        #pragma unroll
        for (int k=0;k<d3;++k)
          z[k] += xv * s_yc[nl][YCOFF[p] + i*d3 + k];
      }
      float* zp = &s_z[(nl*65 + u)*ZS];
      #pragma unroll
      for (int k=0;k<d3;++k) zp[k]=z[k];
    }
    __syncthreads();

    // ---- stage 3: acc[w][k] += sum_u Z[nl3][u][k] * Wp[u][w] ----
    const float* wp = W + p*4096 + w4*4;
    const float* zb = &s_z[nl3*65*ZS];
    #pragma unroll 4
    for (int u=0;u<64;++u){
      const float4 wv = *reinterpret_cast<const float4*>(wp + (size_t)u*64);
      #pragma unroll
      for (int k=0;k<d3;++k){
        float zk = zb[u*ZS + k];
        acc[0][KKB[l3]+k] += zk*wv.x;
        acc[1][KKB[l3]+k] += zk*wv.y;
        acc[2][KKB[l3]+k] += zk*wv.z;
        acc[3][KKB[l3]+k] += zk*wv.w;
      }
    }
  }

  // ---- epilogue: out[n][l3off + w*(2l3+1) + k], all float4 stores ----
  float* op = out + (size_t)(n0 + nl3)*576;
  { // l3=0: op[w]
    float4 v = make_float4(acc[0][0], acc[1][0], acc[2][0], acc[3][0]);
    *reinterpret_cast<float4*>(op + w4*4) = v;
  }
  { // l3=1: op[64 + w*3 + k] -> 12 contiguous floats at 64 + w4*12
    float4 v0 = make_float4(acc[0][1],acc[0][2],acc[0][3],acc[1][1]);
    float4 v1 = make_float4(acc[1][2],acc[1][3],acc[2][1],acc[2][2]);
    float4 v2 = make_float4(acc[2][3],acc[3][1],acc[3][2],acc[3][3]);
    float4* q = reinterpret_cast<float4*>(op + 64 + w4*12);
    q[0]=v0; q[1]=v1; q[2]=v2;
  }
  { // l3=2: op[256 + w*5 + k] -> 20 contiguous floats at 256 + w4*20
    float4 v0 = make_float4(acc[0][4],acc[0][5],acc[0][6],acc[0][7]);
    float4 v1 = make_float4(acc[0][8],acc[1][4],acc[1][5],acc[1][6]);
    float4 v2 = make_float4(acc[1][7],acc[1][8],acc[2][4],acc[2][5]);
    float4 v3 = make_float4(acc[2][6],acc[2][7],acc[2][8],acc[3][4]);
    float4 v4 = make_float4(acc[3][5],acc[3][6],acc[3][7],acc[3][8]);
    float4* q = reinterpret_cast<float4*>(op + 256 + w4*20);
    q[0]=v0; q[1]=v1; q[2]=v2; q[3]=v3; q[4]=v4;
  }
}

// ---------------- launch ----------------
extern "C" void kernel_launch(void* const* d_in, const int* in_sizes, int n_in,
                              void* d_out, int out_size, void* d_ws, size_t ws_size,
                              hipStream_t stream) {
  const float* x = (const float*)d_in[0];
  const float* y = (const float*)d_in[1];
  const float* W = (const float*)d_in[2];
  float* out = (float*)d_out;
  (void)d_ws; (void)ws_size; (void)in_sizes; (void)n_in; (void)out_size;

  CGArg cga;
  compute_cg(cga.v);   // deterministic host-side constant generation (CPU, ~µs; captured by value)

  const int nblocks = 32768 / BN;  // 2048
  hipLaunchKernelGGL(tp_kernel, dim3(nblocks), dim3(256), 0, stream,
                     x, y, W, out, cga);
}

// Round 2
// 149.961 us; speedup vs baseline: 2.0454x; 2.0454x over previous
//
#include <hip/hip_runtime.h>
#include <cmath>
#include <complex>
#include <algorithm>

// ---------------- compile-time path metadata ----------------
#define NPATH 15
constexpr int PL1[NPATH] = {0,0,0, 1,1,1,1,1,1, 2,2,2,2,2,2};
constexpr int PL2[NPATH] = {0,1,2, 0,1,1,1,2,2, 0,1,1,2,2,2};
constexpr int PL3[NPATH] = {0,1,2, 1,0,1,2,1,2, 2,1,2,0,1,2};
constexpr int CGOFF[NPATH] = {0,1,10,35,44,53,80,125,170,245,270,315,390,415,490};
constexpr int CGTOT = 615;
// padded yC layout: per-path row stride pad(d3): 1->1, 3->4, 5->8; bases 4-float aligned
constexpr int YCP[NPATH]  = {0,4,8,16,28,32,44,68,80,104,144,164,204,212,232};
constexpr int YCSTR[NPATH]= {1,4,8,4,1,4,8,4,8,8,4,8,1,4,8};
constexpr int YCROW = 272;                  // floats per batch row
constexpr int YOFF[3] = {0,1,4};

struct CGArg { float v[CGTOT]; };           // alpha-folded real-basis CG (kernarg)

// ---------------- host: exact port of reference CG construction ----------------
static double factd(int n){ double r=1.0; for(int i=2;i<=n;++i) r*=(double)i; return r; }

static double su2_cg(int j1,int m1,int j2,int m2,int j3,int m3){
  if (m3 != m1+m2) return 0.0;
  double c = (double)(2*j3+1) * factd(j1+j2-j3) * factd(j1-j2+j3) * factd(-j1+j2+j3)
             / factd(j1+j2+j3+1);
  c = std::sqrt(c);
  c *= std::sqrt(factd(j3+m3)*factd(j3-m3)*factd(j1-m1)*factd(j1+m1)*factd(j2-m2)*factd(j2+m2));
  double s = 0.0;
  int kmin = std::max(0, std::max(j2-j3-m1, j1-j3+m2));
  int kmax = std::min(j1+j2-j3, std::min(j1-m1, j2+m2));
  for (int k=kmin;k<=kmax;++k){
    double d = factd(k)*factd(j1+j2-j3-k)*factd(j1-m1-k)*factd(j2+m2-k)
             * factd(j3-j2+m1+k)*factd(j3-j1-m2+k);
    s += ((k&1)? -1.0 : 1.0)/d;
  }
  return c*s;
}

static void qmat(int l, std::complex<double>* q){
  int d = 2*l+1;
  for (int a=0;a<d*d;++a) q[a] = std::complex<double>(0.0,0.0);
  const double r2 = 1.0/std::sqrt(2.0);
  for (int m=-l; m<0; ++m){
    q[(l+m)*d + (l-m)] = std::complex<double>(r2, 0.0);
    q[(l+m)*d + (l+m)] = std::complex<double>(0.0, -r2);
  }
  q[l*d + l] = std::complex<double>(1.0,0.0);
  for (int m=1; m<=l; ++m){
    double sg = (m&1)? -1.0 : 1.0;
    q[(l+m)*d + (l+m)] = std::complex<double>(sg*r2, 0.0);
    q[(l+m)*d + (l-m)] = std::complex<double>(0.0, sg*r2);
  }
  std::complex<double> ph = (l==0)? std::complex<double>(1,0)
                        : (l==1)? std::complex<double>(0,-1)
                                : std::complex<double>(-1,0);   // (-i)^l
  for (int a=0;a<d*d;++a) q[a] *= ph;
}

static void compute_cg(float* outv){
  const int npaths_to[3] = {3,6,6};
  for (int p=0;p<NPATH;++p){
    int l1=PL1[p], l2=PL2[p], l3=PL3[p];
    int d1=2*l1+1, d2=2*l2+1, d3=2*l3+1;
    std::complex<double> C[5][5][5];
    for (int a=0;a<5;++a) for(int b=0;b<5;++b) for(int c=0;c<5;++c) C[a][b][c]=std::complex<double>(0,0);
    for (int m1=-l1;m1<=l1;++m1) for (int m2=-l2;m2<=l2;++m2){
      int m3=m1+m2;
      if (std::abs(m3)<=l3) C[l1+m1][l2+m2][l3+m3] = su2_cg(l1,m1,l2,m2,l3,m3);
    }
    std::complex<double> U1[25],U2[25],U3[25];
    qmat(l1,U1); qmat(l2,U2); qmat(l3,U3);
    double Cr[5][5][5]; double nrm=0.0;
    for (int a=0;a<d1;++a) for (int b=0;b<d2;++b) for (int c=0;c<d3;++c){
      std::complex<double> s(0,0);
      for (int i=0;i<d1;++i) for (int j=0;j<d2;++j) for (int k=0;k<d3;++k)
        s += U1[i*d1+a]*U2[j*d2+b]*std::conj(U3[k*d3+c])*C[i][j][k];
      Cr[a][b][c] = s.real();
      nrm += s.real()*s.real();
    }
    nrm = std::sqrt(nrm);
    double alpha = 1.0/std::sqrt(64.0*(double)npaths_to[l3]);
    float* o = outv + CGOFF[p];
    int idx=0;
    for (int a=0;a<d1;++a) for (int b=0;b<d2;++b) for (int c=0;c<d3;++c)
      o[idx++] = (float)(Cr[a][b][c]/nrm*alpha);
  }
}

// ---------------- device ----------------
typedef short bf16x8 __attribute__((ext_vector_type(8)));
typedef float f32x4 __attribute__((ext_vector_type(4)));

__device__ __forceinline__ unsigned cvtpk_bf16(float a, float b){
  unsigned r;
  asm("v_cvt_pk_bf16_f32 %0, %1, %2" : "=v"(r) : "v"(a), "v"(b));
  return r;   // lo16 = bf16(a), hi16 = bf16(b)
}

// z-fragment read: A[row=cl][u = kt*32 + q*8 + j], XOR-swizzled 16B chunks
__device__ __forceinline__ bf16x8 zfrag(const unsigned short* zg, int plane, int kt, int row, int q){
  int c = (kt*4 + q) ^ (row & 7);
  return *reinterpret_cast<const bf16x8*>(zg + (plane*16 + row)*64 + c*8);
}
// W^T fragment: B[u = kt*32 + q*8 + j][w = wt*16 + cl]
__device__ __forceinline__ bf16x8 wfrag(const unsigned short* WT, int p, int wt, int cl, int kt, int q){
  return *reinterpret_cast<const bf16x8*>(WT + p*4096 + (wt*16+cl)*64 + kt*32 + q*8);
}

// stage-2: one path's Z[n, u0..u0+3, k] -> swizzled bf16 LDS
template<int P, int PLANE0, int L1, int D3>
__device__ __forceinline__ void s2path(const float* __restrict__ xr,
                                       const float* __restrict__ ycn,
                                       unsigned short* __restrict__ zg,
                                       int n, int t16)
{
  constexpr int D1 = 2*L1+1;
  float z[4][D3];
  #pragma unroll
  for (int uu=0;uu<4;++uu)
    #pragma unroll
    for (int k=0;k<D3;++k) z[uu][k]=0.f;

  #pragma unroll
  for (int i=0;i<D1;++i){
    float yv[D3];
    const float* yr = ycn + YCP[P] + i*YCSTR[P];
    if constexpr (D3==5){
      float4 t = *reinterpret_cast<const float4*>(yr);
      yv[0]=t.x; yv[1]=t.y; yv[2]=t.z; yv[3]=t.w; yv[4]=yr[4];
    } else if constexpr (D3==3){
      float2 t = *reinterpret_cast<const float2*>(yr);
      yv[0]=t.x; yv[1]=t.y; yv[2]=yr[2];
    } else {
      yv[0]=yr[0];
    }
    #pragma unroll
    for (int uu=0;uu<4;++uu){
      float xv = xr[uu*D1+i];
      #pragma unroll
      for (int k=0;k<D3;++k) z[uu][k] += xv*yv[k];
    }
  }
  const int swz = (((t16>>1) ^ (n&7))<<3) + ((t16&1)<<2);
  #pragma unroll
  for (int k=0;k<D3;++k){
    uint2 w;
    w.x = cvtpk_bf16(z[0][k], z[1][k]);
    w.y = cvtpk_bf16(z[2][k], z[3][k]);
    *reinterpret_cast<uint2*>(zg + ((PLANE0+k)*16 + n)*64 + swz) = w;
  }
}

__global__ __launch_bounds__(256, 2)
void tp_kernel(const float* __restrict__ x, const float* __restrict__ y,
               const unsigned short* __restrict__ WT, float* __restrict__ out, CGArg cga)
{
  __shared__ __align__(16) unsigned short s_z[30720];  // 61440 B; unioned with x-staging
  __shared__ float s_yc[16*YCROW];                     // 17408 B
  __shared__ float s_y[16][9];

  const int tid = threadIdx.x;
  const int n0 = blockIdx.x * 16;
  float* s_x = reinterpret_cast<float*>(s_z);          // [16][576] during load phase

  // coop loads: x (float4, coalesced) and y
  {
    const float4* xg = reinterpret_cast<const float4*>(x + (size_t)n0*576);
    float4* xs = reinterpret_cast<float4*>(s_x);
    #pragma unroll
    for (int i=0;i<9;++i) xs[i*256+tid] = xg[i*256+tid];
    if (tid < 144){
      int nl = tid/9, j = tid - nl*9;
      s_y[nl][j] = y[(size_t)(n0+nl)*9 + j];
    }
  }
  __syncthreads();

  // stage 1: yc[n][p][i][k] = sum_j y[n][j] * cg[p][i][j][k]   (alpha folded)
  #pragma unroll
  for (int p=0;p<NPATH;++p){
    const int d1=2*PL1[p]+1, d2=2*PL2[p]+1, d3=2*PL3[p]+1;
    const int cnt = 16*d1*d3;
    for (int idx=tid; idx<cnt; idx+=256){
      int n = idx/(d1*d3);
      int r = idx - n*(d1*d3);
      int i = r/d3;
      int k = r - i*d3;
      float s=0.f;
      for (int j=0;j<d2;++j)
        s += s_y[n][YOFF[PL2[p]]+j]*cga.v[CGOFF[p]+(i*d2+j)*d3+k];
      s_yc[n*YCROW + YCP[p] + i*YCSTR[p] + k] = s;
    }
  }

  // x -> registers: this thread owns (n = tid>>4, u = 4*(tid&15)..+3)
  const int n_s2 = tid>>4, t16 = tid&15;
  float xr0[4], xr1[12], xr2[20];
  {
    const float* xb = s_x + n_s2*576;
    *reinterpret_cast<float4*>(xr0) = *reinterpret_cast<const float4*>(xb + t16*4);
    #pragma unroll
    for (int i=0;i<3;++i)
      *reinterpret_cast<float4*>(xr1+4*i) = *reinterpret_cast<const float4*>(xb + 64 + t16*12 + 4*i);
    #pragma unroll
    for (int i=0;i<5;++i)
      *reinterpret_cast<float4*>(xr2+4*i) = *reinterpret_cast<const float4*>(xb + 256 + t16*20 + 4*i);
  }
  __syncthreads();   // s_yc ready; s_x consumed -> s_z reusable

  const int lane = tid & 63, wid = tid >> 6;
  const int cl = lane & 15, q = lane >> 4;
  const float* ycn = s_yc + n_s2*YCROW;

  const f32x4 zero4 = {0.f,0.f,0.f,0.f};
  f32x4 acc0 = zero4;                               // (l3=0, k=0, wt=wid)
  f32x4 acc1[4] = {zero4,zero4,zero4,zero4};        // (l3=1, k=wid, wt)   [waves 0-2]
  f32x4 acc2[4] = {zero4,zero4,zero4,zero4};        // (l3=2, k=wid, wt)
  f32x4 accb = zero4;                               // (l3=2, k=4,  wt=wid)

  // ================= group 0 : l3=0 =================
  s2path<0,0,0,1>(xr0, ycn, s_z, n_s2, t16);
  s2path<4,1,1,1>(xr1, ycn, s_z, n_s2, t16);
  s2path<12,2,2,1>(xr2, ycn, s_z, n_s2, t16);
  __syncthreads();
  {
    constexpr int GP[3] = {0,4,12};
    #pragma unroll
    for (int pg=0;pg<3;++pg)
      #pragma unroll
      for (int kt=0;kt<2;++kt){
        bf16x8 a = zfrag(s_z, pg, kt, cl, q);
        bf16x8 b = wfrag(WT, GP[pg], wid, cl, kt, q);
        acc0 = __builtin_amdgcn_mfma_f32_16x16x32_bf16(a, b, acc0, 0,0,0);
      }
  }
  __syncthreads();

  // ================= group 1 : l3=1 =================
  s2path<1,0,0,3>(xr0, ycn, s_z, n_s2, t16);
  s2path<3,3,1,3>(xr1, ycn, s_z, n_s2, t16);
  s2path<5,6,1,3>(xr1, ycn, s_z, n_s2, t16);
  s2path<7,9,1,3>(xr1, ycn, s_z, n_s2, t16);
  s2path<10,12,2,3>(xr2, ycn, s_z, n_s2, t16);
  s2path<13,15,2,3>(xr2, ycn, s_z, n_s2, t16);
  __syncthreads();
  if (wid < 3){
    constexpr int GP[6] = {1,3,5,7,10,13};
    #pragma unroll
    for (int pg=0;pg<6;++pg)
      #pragma unroll
      for (int kt=0;kt<2;++kt){
        bf16x8 a = zfrag(s_z, pg*3 + wid, kt, cl, q);
        #pragma unroll
        for (int wt=0;wt<4;++wt){
          bf16x8 b = wfrag(WT, GP[pg], wt, cl, kt, q);
          acc1[wt] = __builtin_amdgcn_mfma_f32_16x16x32_bf16(a, b, acc1[wt], 0,0,0);
        }
      }
  }
  __syncthreads();

  // ================= group 2 : l3=2 =================
  s2path<2,0,0,5>(xr0, ycn, s_z, n_s2, t16);
  s2path<6,5,1,5>(xr1, ycn, s_z, n_s2, t16);
  s2path<8,10,1,5>(xr1, ycn, s_z, n_s2, t16);
  s2path<9,15,2,5>(xr2, ycn, s_z, n_s2, t16);
  s2path<11,20,2,5>(xr2, ycn, s_z, n_s2, t16);
  s2path<14,25,2,5>(xr2, ycn, s_z, n_s2, t16);
  __syncthreads();
  {
    constexpr int GP[6] = {2,6,8,9,11,14};
    #pragma unroll
    for (int pg=0;pg<6;++pg)
      #pragma unroll
      for (int kt=0;kt<2;++kt){
        bf16x8 a = zfrag(s_z, pg*5 + wid, kt, cl, q);
        #pragma unroll
        for (int wt=0;wt<4;++wt){
          bf16x8 b = wfrag(WT, GP[pg], wt, cl, kt, q);
          acc2[wt] = __builtin_amdgcn_mfma_f32_16x16x32_bf16(a, b, acc2[wt], 0,0,0);
        }
        bf16x8 a4 = zfrag(s_z, pg*5 + 4, kt, cl, q);       // shared k=4 plane, wt=wid slice
        bf16x8 b4 = wfrag(WT, GP[pg], wid, cl, kt, q);
        accb = __builtin_amdgcn_mfma_f32_16x16x32_bf16(a4, b4, accb, 0,0,0);
      }
  }

  // ================= epilogue =================
  // D layout: row n = q*4 + reg, col w = wt*16 + cl
  #pragma unroll
  for (int r=0;r<4;++r){
    float* orow = out + (size_t)(n0 + q*4 + r)*576;
    orow[wid*16 + cl] = acc0[r];
    if (wid < 3){
      #pragma unroll
      for (int wt=0;wt<4;++wt)
        orow[64 + (wt*16+cl)*3 + wid] = acc1[wt][r];
    }
    #pragma unroll
    for (int wt=0;wt<4;++wt)
      orow[256 + (wt*16+cl)*5 + wid] = acc2[wt][r];
    orow[256 + (wid*16+cl)*5 + 4] = accb[r];
  }
}

// W[p][u][w] (fp32) -> WT[p][w][u] (bf16, RNE) once per launch
__global__ void wt_kernel(const float* __restrict__ W, unsigned short* __restrict__ WT){
  int t = blockIdx.x*256 + threadIdx.x;      // 61440 total
  int p = t >> 12, r = t & 4095, w = r >> 6, u = r & 63;
  float f = W[(p<<12) + (u<<6) + w];
  unsigned fu = __builtin_bit_cast(unsigned, f);
  unsigned rr = (fu + 0x7FFFu + ((fu>>16)&1u)) >> 16;
  WT[t] = (unsigned short)rr;
}

// ---------------- launch ----------------
extern "C" void kernel_launch(void* const* d_in, const int* in_sizes, int n_in,
                              void* d_out, int out_size, void* d_ws, size_t ws_size,
                              hipStream_t stream) {
  const float* x = (const float*)d_in[0];
  const float* y = (const float*)d_in[1];
  const float* W = (const float*)d_in[2];
  float* out = (float*)d_out;
  (void)in_sizes; (void)n_in; (void)out_size; (void)ws_size;

  unsigned short* WT = (unsigned short*)d_ws;   // 61440 * 2 B

  CGArg cga;
  compute_cg(cga.v);

  hipLaunchKernelGGL(wt_kernel, dim3(240), dim3(256), 0, stream, W, WT);
  hipLaunchKernelGGL(tp_kernel, dim3(2048), dim3(256), 0, stream, x, y, WT, out, cga);
}

// Round 3
// 79.369 us; speedup vs baseline: 3.8646x; 1.8894x over previous
//
#include <hip/hip_runtime.h>
#include <cmath>
#include <complex>
#include <algorithm>

// ---------------- compile-time path metadata ----------------
#define NPATH 15
constexpr int PL1[NPATH] = {0,0,0, 1,1,1,1,1,1, 2,2,2,2,2,2};
constexpr int PL2[NPATH] = {0,1,2, 0,1,1,1,2,2, 0,1,1,2,2,2};
constexpr int PL3[NPATH] = {0,1,2, 1,0,1,2,1,2, 2,1,2,0,1,2};
constexpr int CGOFF[NPATH] = {0,1,10,35,44,53,80,125,170,245,270,315,390,415,490};
constexpr int CGTOT = 615;
// yc layout: i-contiguous, stride per k = pad(d1) (1,4,8); bases 4-float aligned
constexpr int YB[NPATH]  = {0,4,8,16,28,32,44,64,76,96,136,160,200,208,232};
constexpr int PD1[NPATH] = {1,1,1,4,4,4,4,4,4,8,8,8,8,8,8};
constexpr int YCROW = 276;        // floats per batch row (276*4B: 4-row stride -> 2-way banks, free)
constexpr int YOFF[3] = {0,1,4};
constexpr int KKB[3]  = {0,1,4};  // acc k-base per l3

struct CGArg { float v[CGTOT]; }; // alpha-folded real-basis CG (kernarg)

// ---------------- host: exact port of reference CG construction ----------------
static double factd(int n){ double r=1.0; for(int i=2;i<=n;++i) r*=(double)i; return r; }

static double su2_cg(int j1,int m1,int j2,int m2,int j3,int m3){
  if (m3 != m1+m2) return 0.0;
  double c = (double)(2*j3+1) * factd(j1+j2-j3) * factd(j1-j2+j3) * factd(-j1+j2+j3)
             / factd(j1+j2+j3+1);
  c = std::sqrt(c);
  c *= std::sqrt(factd(j3+m3)*factd(j3-m3)*factd(j1-m1)*factd(j1+m1)*factd(j2-m2)*factd(j2+m2));
  double s = 0.0;
  int kmin = std::max(0, std::max(j2-j3-m1, j1-j3+m2));
  int kmax = std::min(j1+j2-j3, std::min(j1-m1, j2+m2));
  for (int k=kmin;k<=kmax;++k){
    double d = factd(k)*factd(j1+j2-j3-k)*factd(j1-m1-k)*factd(j2+m2-k)
             * factd(j3-j2+m1+k)*factd(j3-j1-m2+k);
    s += ((k&1)? -1.0 : 1.0)/d;
  }
  return c*s;
}

static void qmat(int l, std::complex<double>* q){
  int d = 2*l+1;
  for (int a=0;a<d*d;++a) q[a] = std::complex<double>(0.0,0.0);
  const double r2 = 1.0/std::sqrt(2.0);
  for (int m=-l; m<0; ++m){
    q[(l+m)*d + (l-m)] = std::complex<double>(r2, 0.0);
    q[(l+m)*d + (l+m)] = std::complex<double>(0.0, -r2);
  }
  q[l*d + l] = std::complex<double>(1.0,0.0);
  for (int m=1; m<=l; ++m){
    double sg = (m&1)? -1.0 : 1.0;
    q[(l+m)*d + (l+m)] = std::complex<double>(sg*r2, 0.0);
    q[(l+m)*d + (l-m)] = std::complex<double>(0.0, sg*r2);
  }
  std::complex<double> ph = (l==0)? std::complex<double>(1,0)
                        : (l==1)? std::complex<double>(0,-1)
                                : std::complex<double>(-1,0);   // (-i)^l
  for (int a=0;a<d*d;++a) q[a] *= ph;
}

static void compute_cg(float* outv){
  const int npaths_to[3] = {3,6,6};
  for (int p=0;p<NPATH;++p){
    int l1=PL1[p], l2=PL2[p], l3=PL3[p];
    int d1=2*l1+1, d2=2*l2+1, d3=2*l3+1;
    std::complex<double> C[5][5][5];
    for (int a=0;a<5;++a) for(int b=0;b<5;++b) for(int c=0;c<5;++c) C[a][b][c]=std::complex<double>(0,0);
    for (int m1=-l1;m1<=l1;++m1) for (int m2=-l2;m2<=l2;++m2){
      int m3=m1+m2;
      if (std::abs(m3)<=l3) C[l1+m1][l2+m2][l3+m3] = su2_cg(l1,m1,l2,m2,l3,m3);
    }
    std::complex<double> U1[25],U2[25],U3[25];
    qmat(l1,U1); qmat(l2,U2); qmat(l3,U3);
    double Cr[5][5][5]; double nrm=0.0;
    for (int a=0;a<d1;++a) for (int b=0;b<d2;++b) for (int c=0;c<d3;++c){
      std::complex<double> s(0,0);
      for (int i=0;i<d1;++i) for (int j=0;j<d2;++j) for (int k=0;k<d3;++k)
        s += U1[i*d1+a]*U2[j*d2+b]*std::conj(U3[k*d3+c])*C[i][j][k];
      Cr[a][b][c] = s.real();
      nrm += s.real()*s.real();
    }
    nrm = std::sqrt(nrm);
    double alpha = 1.0/std::sqrt(64.0*(double)npaths_to[l3]);
    float* o = outv + CGOFF[p];
    int idx=0;
    for (int a=0;a<d1;++a) for (int b=0;b<d2;++b) for (int c=0;c<d3;++c)
      o[idx++] = (float)(Cr[a][b][c]/nrm*alpha);
  }
}

// ---------------- device ----------------
typedef short bf16x8 __attribute__((ext_vector_type(8)));
typedef float f32x4 __attribute__((ext_vector_type(4)));

__device__ __forceinline__ unsigned cvtpk_bf16(float a, float b){
  unsigned r;
  asm("v_cvt_pk_bf16_f32 %0, %1, %2" : "=v"(r) : "v"(a), "v"(b));
  return r;   // lo16 = bf16(a), hi16 = bf16(b)
}

// A-fragment: lane (cl,q) holds A[row=cl][u=kt*32+q*8 ..+7]; XOR-swizzled 16B chunks (R2-verified)
__device__ __forceinline__ bf16x8 afrag(const unsigned short* s_xt, int plane, int kt, int row, int q){
  int c = (kt*4 + q) ^ (row & 7);
  return *reinterpret_cast<const bf16x8*>(s_xt + (plane*16 + row)*64 + c*8);
}
// B-fragment: lane (cl,q) holds B[u=kt*32+q*8..+7][w=wt*16+cl] from WT[p][w][u]
__device__ __forceinline__ bf16x8 wfrag(const unsigned short* WT, int p, int wt, int cl, int kt, int q){
  return *reinterpret_cast<const bf16x8*>(WT + p*4096 + (wt*16+cl)*64 + kt*32 + q*8);
}
// xT write: thread (n,t16) writes u-quad 4*t16.. of a plane (swizzle matches afrag)
__device__ __forceinline__ void xt_write(unsigned short* s_xt, int plane, int n, int t16,
                                         float a, float b, float c, float d){
  const int swz = (((t16>>1)^(n&7))<<3) + ((t16&1)<<2);
  uint2 w; w.x = cvtpk_bf16(a,b); w.y = cvtpk_bf16(c,d);
  *reinterpret_cast<uint2*>(s_xt + (plane*16 + n)*64 + swz) = w;
}

template<int L1>
__device__ __forceinline__ void load_afrags(const unsigned short* s_xt, bf16x8* a, int cl, int q){
  constexpr int D1 = 2*L1+1;
  constexpr int PB = (L1==0)?0:(L1==1)?1:4;   // plane base
  #pragma unroll
  for (int i=0;i<D1;++i)
    #pragma unroll
    for (int kt=0;kt<2;++kt)
      a[2*i+kt] = afrag(s_xt, PB+i, kt, cl, q);
}

// one path: T_p[i] = x-plane_i @ W_p (MFMA over u), then acc[k] += T[i]*yc[n,i,k]
template<int P, int L1, int L3>
__device__ __forceinline__ void do_path(const unsigned short* __restrict__ WT,
                                        const bf16x8* a, const float* __restrict__ ycq,
                                        f32x4* acc, int wid, int cl, int q)
{
  constexpr int D1 = 2*L1+1, D3 = 2*L3+1;
  constexpr int PD = PD1[P];
  const f32x4 z4 = {0.f,0.f,0.f,0.f};
  bf16x8 b0 = wfrag(WT, P, wid, cl, 0, q);
  bf16x8 b1 = wfrag(WT, P, wid, cl, 1, q);
  f32x4 T[D1];
  #pragma unroll
  for (int i=0;i<D1;++i){
    T[i] = __builtin_amdgcn_mfma_f32_16x16x32_bf16(a[2*i],   b0, z4,  0,0,0);
    T[i] = __builtin_amdgcn_mfma_f32_16x16x32_bf16(a[2*i+1], b1, T[i],0,0,0);
  }
  #pragma unroll
  for (int r=0;r<4;++r){
    const float* yr = ycq + r*YCROW + YB[P];   // yc row for n = q*4+r
    #pragma unroll
    for (int k=0;k<D3;++k){
      const float* ya = yr + k*PD;
      if constexpr (D1==1){
        acc[KKB[L3]+k][r] += T[0][r]*ya[0];
      } else if constexpr (D1==3){
        float4 yv = *reinterpret_cast<const float4*>(ya);
        acc[KKB[L3]+k][r] += T[0][r]*yv.x + T[1][r]*yv.y + T[2][r]*yv.z;
      } else {
        float4 yv = *reinterpret_cast<const float4*>(ya);
        float y4 = ya[4];
        acc[KKB[L3]+k][r] += T[0][r]*yv.x + T[1][r]*yv.y + T[2][r]*yv.z
                           + T[3][r]*yv.w + T[4][r]*y4;
      }
    }
  }
}

__global__ __launch_bounds__(256, 3)
void tp_kernel(const float* __restrict__ x, const float* __restrict__ y,
               const unsigned short* __restrict__ WT, float* __restrict__ out, CGArg cga)
{
  __shared__ __align__(16) unsigned short s_xt[9*16*64];  // 18432 B: bf16 x planes (l1=0:1, l1=1:3, l1=2:5)
  __shared__ float s_yc[16*YCROW];                        // 17664 B
  __shared__ float s_y[16][9];

  const int tid = threadIdx.x;
  const int n0 = blockIdx.x * 16;
  const int n_s = tid>>4, t16 = tid&15;

  // issue all x loads first (latency overlaps y/yc work)
  const float* xb = x + (size_t)(n0 + n_s)*576;
  float4 xr0 = *reinterpret_cast<const float4*>(xb + t16*4);
  float4 xr1[3], xr2[5];
  #pragma unroll
  for (int i=0;i<3;++i) xr1[i] = *reinterpret_cast<const float4*>(xb + 64 + t16*12 + 4*i);
  #pragma unroll
  for (int i=0;i<5;++i) xr2[i] = *reinterpret_cast<const float4*>(xb + 256 + t16*20 + 4*i);

  if (tid < 144){
    int nl = tid/9, j = tid - nl*9;
    s_y[nl][j] = y[(size_t)(n0+nl)*9 + j];
  }
  __syncthreads();

  // stage 1: yc[n][YB[p] + k*PD1[p] + i] = sum_j y[n][j]*cg[p][i][j][k]  (alpha folded)
  #pragma unroll
  for (int p=0;p<NPATH;++p){
    const int d1=2*PL1[p]+1, d2=2*PL2[p]+1, d3=2*PL3[p]+1;
    const int cnt = 16*d1*d3;
    for (int idx=tid; idx<cnt; idx+=256){
      int n = idx/(d1*d3);
      int r = idx - n*(d1*d3);
      int i = r/d3;
      int k = r - i*d3;
      float s=0.f;
      for (int j=0;j<d2;++j)
        s += s_y[n][YOFF[PL2[p]]+j]*cga.v[CGOFF[p]+(i*d2+j)*d3+k];
      s_yc[n*YCROW + YB[p] + k*PD1[p] + i] = s;
    }
  }

  // x -> bf16 planes in LDS (no barrier needed before: s_xt untouched so far)
  xt_write(s_xt, 0, n_s, t16, xr0.x, xr0.y, xr0.z, xr0.w);
  {
    float v[4][5];
    #pragma unroll
    for (int uu=0;uu<4;++uu){
      #pragma unroll
      for (int i=0;i<3;++i) v[uu][i] = reinterpret_cast<const float*>(xr1)[uu*3+i];
    }
    #pragma unroll
    for (int i=0;i<3;++i) xt_write(s_xt, 1+i, n_s, t16, v[0][i], v[1][i], v[2][i], v[3][i]);
    #pragma unroll
    for (int uu=0;uu<4;++uu){
      #pragma unroll
      for (int i=0;i<5;++i) v[uu][i] = reinterpret_cast<const float*>(xr2)[uu*5+i];
    }
    #pragma unroll
    for (int i=0;i<5;++i) xt_write(s_xt, 4+i, n_s, t16, v[0][i], v[1][i], v[2][i], v[3][i]);
  }
  __syncthreads();   // xT + yc ready

  const int lane = tid & 63, wid = tid >> 6;
  const int cl = lane & 15, q = lane >> 4;
  const float* ycq = s_yc + q*4*YCROW;

  const f32x4 z4 = {0.f,0.f,0.f,0.f};
  f32x4 acc[9] = {z4,z4,z4,z4,z4,z4,z4,z4,z4};   // k: 0 | 1..3 | 4..8

  // ---- main loop: no barriers; wave owns w-tile wid ----
  {
    bf16x8 a0[2];  load_afrags<0>(s_xt, a0, cl, q);
    do_path<0,0,0>(WT, a0, ycq, acc, wid, cl, q);
    do_path<1,0,1>(WT, a0, ycq, acc, wid, cl, q);
    do_path<2,0,2>(WT, a0, ycq, acc, wid, cl, q);
  }
  {
    bf16x8 a1[6];  load_afrags<1>(s_xt, a1, cl, q);
    do_path<3,1,1>(WT, a1, ycq, acc, wid, cl, q);
    do_path<4,1,0>(WT, a1, ycq, acc, wid, cl, q);
    do_path<5,1,1>(WT, a1, ycq, acc, wid, cl, q);
    do_path<6,1,2>(WT, a1, ycq, acc, wid, cl, q);
    do_path<7,1,1>(WT, a1, ycq, acc, wid, cl, q);
    do_path<8,1,2>(WT, a1, ycq, acc, wid, cl, q);
  }
  {
    bf16x8 a2[10]; load_afrags<2>(s_xt, a2, cl, q);
    do_path<9,2,2>(WT, a2, ycq, acc, wid, cl, q);
    do_path<10,2,1>(WT, a2, ycq, acc, wid, cl, q);
    do_path<11,2,2>(WT, a2, ycq, acc, wid, cl, q);
    do_path<12,2,0>(WT, a2, ycq, acc, wid, cl, q);
    do_path<13,2,1>(WT, a2, ycq, acc, wid, cl, q);
    do_path<14,2,2>(WT, a2, ycq, acc, wid, cl, q);
  }

  // ---- epilogue: D row n = q*4+r, col w = wid*16+cl ----
  const int wc = wid*16 + cl;
  #pragma unroll
  for (int r=0;r<4;++r){
    float* orow = out + (size_t)(n0 + q*4 + r)*576;
    orow[wc] = acc[0][r];
    #pragma unroll
    for (int k=0;k<3;++k) orow[64 + wc*3 + k]  = acc[1+k][r];
    #pragma unroll
    for (int k=0;k<5;++k) orow[256 + wc*5 + k] = acc[4+k][r];
  }
}

// W[p][u][w] (fp32) -> WT[p][w][u] (bf16, RNE) once per launch
__global__ void wt_kernel(const float* __restrict__ W, unsigned short* __restrict__ WT){
  int t = blockIdx.x*256 + threadIdx.x;      // 61440 total
  int p = t >> 12, r = t & 4095, w = r >> 6, u = r & 63;
  float f = W[(p<<12) + (u<<6) + w];
  unsigned fu = __builtin_bit_cast(unsigned, f);
  unsigned rr = (fu + 0x7FFFu + ((fu>>16)&1u)) >> 16;
  WT[t] = (unsigned short)rr;
}

// ---------------- launch ----------------
extern "C" void kernel_launch(void* const* d_in, const int* in_sizes, int n_in,
                              void* d_out, int out_size, void* d_ws, size_t ws_size,
                              hipStream_t stream) {
  const float* x = (const float*)d_in[0];
  const float* y = (const float*)d_in[1];
  const float* W = (const float*)d_in[2];
  float* out = (float*)d_out;
  (void)in_sizes; (void)n_in; (void)out_size; (void)ws_size;

  unsigned short* WT = (unsigned short*)d_ws;   // 61440 * 2 B

  CGArg cga;
  compute_cg(cga.v);

  hipLaunchKernelGGL(wt_kernel, dim3(240), dim3(256), 0, stream, W, WT);
  hipLaunchKernelGGL(tp_kernel, dim3(2048), dim3(256), 0, stream, x, y, WT, out, cga);
}